// Round 1
// baseline (259.955 us; speedup 1.0000x reference)
//
#include <hip/hip_runtime.h>

typedef unsigned short u16;
typedef short bf16x8 __attribute__((ext_vector_type(8)));
typedef float f32x4 __attribute__((ext_vector_type(4)));

// float -> bf16 bits, round-to-nearest-even (inputs never NaN here)
__device__ __forceinline__ u16 f2bf(float f) {
  union { float f; unsigned int u; } a; a.f = f;
  unsigned int r = a.u + 0x7FFFu + ((a.u >> 16) & 1u);
  return (u16)(r >> 16);
}

// ---- K1/K5: Y[o][p] = sum_c W[o*192+c] * X[c*4096+p]; o-tile = 24 rows ----
__global__ __launch_bounds__(256) void gemm192(const float* __restrict__ W,
                                               const float* __restrict__ X,
                                               float* __restrict__ Y) {
  __shared__ float wlds[24 * 192];
  int tid = threadIdx.x;
  int p = blockIdx.x * 256 + tid;
  int o0 = blockIdx.y * 24;
  for (int i = tid; i < 24 * 192; i += 256) wlds[i] = W[o0 * 192 + i];
  __syncthreads();
  float acc[24];
  #pragma unroll
  for (int i = 0; i < 24; ++i) acc[i] = 0.f;
  for (int c = 0; c < 192; c += 4) {
    float x0 = X[(c + 0) * 4096 + p];
    float x1 = X[(c + 1) * 4096 + p];
    float x2 = X[(c + 2) * 4096 + p];
    float x3 = X[(c + 3) * 4096 + p];
    #pragma unroll
    for (int oo = 0; oo < 24; ++oo) {
      const float4* wv = (const float4*)&wlds[oo * 192 + c];  // broadcast b128
      acc[oo] = fmaf(wv->x, x0, fmaf(wv->y, x1, fmaf(wv->z, x2, fmaf(wv->w, x3, acc[oo]))));
    }
  }
  #pragma unroll
  for (int oo = 0; oo < 24; ++oo) Y[(size_t)(o0 + oo) * 4096 + p] = acc[oo];
}

// ---- K2: depthwise 3x3, pad=1, on [576][64][64] ----
__global__ __launch_bounds__(256) void dwconv3(const float* __restrict__ in,
                                               const float* __restrict__ w,
                                               float* __restrict__ out) {
  int idx = blockIdx.x * 256 + threadIdx.x;  // c*4096 + p
  int c = idx >> 12;
  int p = idx & 4095;
  int y = p >> 6, x = p & 63;
  const float* wc = w + c * 9;
  const float* ic = in + (size_t)c * 4096;
  float s = 0.f;
  #pragma unroll
  for (int i = 0; i < 3; ++i) {
    int yy = y + i - 1;
    if ((unsigned)yy >= 64u) continue;
    #pragma unroll
    for (int j = 0; j < 3; ++j) {
      int xx = x + j - 1;
      if ((unsigned)xx >= 64u) continue;
      s = fmaf(wc[i * 3 + j], ic[yy * 64 + xx], s);
    }
  }
  out[idx] = s;
}

// ---- K3: L2-normalize q,k per (head,pixel); pack bf16 rows [h][p][32] (d padded 24->32 w/ 0) ----
// SCALE*log2(e) folded into Q so attention uses exp2().
__global__ __launch_bounds__(256) void normpack(const float* __restrict__ qkv,
                                                u16* __restrict__ Qh,
                                                u16* __restrict__ Kh) {
  int idx = blockIdx.x * 256 + threadIdx.x;  // 8*4096
  int h = idx >> 12;
  int p = idx & 4095;
  const float QSC = 0.20412414523193154f * 1.4426950408889634f;  // 24^-0.5 * log2(e)
  float qv[24], kv[24];
  float sq = 0.f, sk = 0.f;
  #pragma unroll
  for (int d = 0; d < 24; ++d) {
    qv[d] = qkv[(size_t)(h * 24 + d) * 4096 + p];
    sq = fmaf(qv[d], qv[d], sq);
  }
  #pragma unroll
  for (int d = 0; d < 24; ++d) {
    kv[d] = qkv[(size_t)(192 + h * 24 + d) * 4096 + p];
    sk = fmaf(kv[d], kv[d], sk);
  }
  float iq = QSC / fmaxf(sqrtf(sq), 1e-12f);  // F.normalize: x / max(||x||, eps)
  float ik = 1.0f / fmaxf(sqrtf(sk), 1e-12f);
  u16* qrow = Qh + (size_t)(h * 4096 + p) * 32;
  u16* krow = Kh + (size_t)(h * 4096 + p) * 32;
  #pragma unroll
  for (int d = 0; d < 24; ++d) { qrow[d] = f2bf(qv[d] * iq); krow[d] = f2bf(kv[d] * ik); }
  #pragma unroll
  for (int d = 24; d < 32; ++d) { qrow[d] = 0; krow[d] = 0; }
}

// ---- K3b: V transposed pack: Vt[h][d(32)][p] bf16, rows d>=24 zeroed ----
__global__ __launch_bounds__(256) void vpack(const float* __restrict__ qkv,
                                             u16* __restrict__ Vt) {
  int idx = blockIdx.x * 256 + threadIdx.x;  // 8*32*4096
  int p = idx & 4095;
  int d = (idx >> 12) & 31;
  int h = idx >> 17;
  float v = (d < 24) ? qkv[(size_t)(384 + h * 24 + d) * 4096 + p] : 0.f;
  Vt[idx] = f2bf(v);
}

// ---- K4: flash attention (no-max softmax; logits bounded by +-0.204) ----
// Block = 1 head x 64 queries, 4 waves (16 q-rows each), loops 64-key tiles.
__global__ __launch_bounds__(256) void attn(const u16* __restrict__ Qh,
                                            const u16* __restrict__ Kh,
                                            const u16* __restrict__ Vt,
                                            float* __restrict__ Y) {
  __shared__ u16 Pl[64 * 72];   // P round-trip, wave-private 16-row strips, stride 72 (16B-aligned rows)
  __shared__ float Ol[24 * 65]; // epilogue transpose
  int tid = threadIdx.x;
  int wave = tid >> 6, lane = tid & 63;
  int lo = lane & 15, hi = lane >> 4;
  int head = blockIdx.x & 7;            // consecutive blocks -> different heads -> XCD locality
  int q0 = (blockIdx.x >> 3) * 64;

  bf16x8 qf = *(const bf16x8*)(Qh + ((size_t)(head * 4096 + q0 + wave * 16 + lo) * 32 + hi * 8));

  const u16* Kb = Kh + (size_t)head * 4096 * 32;
  const u16* Vb = Vt + (size_t)head * 32 * 4096;

  f32x4 oacc0 = {0.f, 0.f, 0.f, 0.f};
  f32x4 oacc1 = {0.f, 0.f, 0.f, 0.f};
  float rs[4] = {0.f, 0.f, 0.f, 0.f};

  bf16x8 kf[4], vf[4];
  #pragma unroll
  for (int j = 0; j < 4; ++j)
    kf[j] = *(const bf16x8*)(Kb + (size_t)(j * 16 + lo) * 32 + hi * 8);
  #pragma unroll
  for (int c = 0; c < 2; ++c)
    #pragma unroll
    for (int n = 0; n < 2; ++n)
      vf[c * 2 + n] = *(const bf16x8*)(Vb + (size_t)(n * 16 + lo) * 4096 + c * 32 + hi * 8);

  u16* Pw = Pl + (wave * 16 + hi * 4) * 72 + lo;        // C-layout scatter base
  const u16* Pr = Pl + (wave * 16 + lo) * 72 + hi * 8;  // A-layout gather base

  for (int it = 0; it < 64; ++it) {
    int k1 = (it < 63) ? (it + 1) * 64 : 0;  // prefetch next tile (wraps harmlessly at end)
    bf16x8 kn[4], vn[4];
    #pragma unroll
    for (int j = 0; j < 4; ++j)
      kn[j] = *(const bf16x8*)(Kb + (size_t)(k1 + j * 16 + lo) * 32 + hi * 8);
    #pragma unroll
    for (int c = 0; c < 2; ++c)
      #pragma unroll
      for (int n = 0; n < 2; ++n)
        vn[c * 2 + n] = *(const bf16x8*)(Vb + (size_t)(n * 16 + lo) * 4096 + k1 + c * 32 + hi * 8);

    f32x4 z = {0.f, 0.f, 0.f, 0.f};
    f32x4 s0 = __builtin_amdgcn_mfma_f32_16x16x32_bf16(qf, kf[0], z, 0, 0, 0);
    f32x4 s1 = __builtin_amdgcn_mfma_f32_16x16x32_bf16(qf, kf[1], z, 0, 0, 0);
    f32x4 s2 = __builtin_amdgcn_mfma_f32_16x16x32_bf16(qf, kf[2], z, 0, 0, 0);
    f32x4 s3 = __builtin_amdgcn_mfma_f32_16x16x32_bf16(qf, kf[3], z, 0, 0, 0);

    #pragma unroll
    for (int r = 0; r < 4; ++r) {
      float p0 = exp2f(s0[r]);
      float p1 = exp2f(s1[r]);
      float p2 = exp2f(s2[r]);
      float p3 = exp2f(s3[r]);
      rs[r] += (p0 + p1) + (p2 + p3);
      Pw[r * 72 + 0]  = f2bf(p0);
      Pw[r * 72 + 16] = f2bf(p1);
      Pw[r * 72 + 32] = f2bf(p2);
      Pw[r * 72 + 48] = f2bf(p3);
    }
    // wave-private LDS: in-order per wave, no barrier needed
    bf16x8 a0 = *(const bf16x8*)(Pr);
    bf16x8 a1 = *(const bf16x8*)(Pr + 32);
    oacc0 = __builtin_amdgcn_mfma_f32_16x16x32_bf16(a0, vf[0], oacc0, 0, 0, 0);
    oacc1 = __builtin_amdgcn_mfma_f32_16x16x32_bf16(a0, vf[1], oacc1, 0, 0, 0);
    oacc0 = __builtin_amdgcn_mfma_f32_16x16x32_bf16(a1, vf[2], oacc0, 0, 0, 0);
    oacc1 = __builtin_amdgcn_mfma_f32_16x16x32_bf16(a1, vf[3], oacc1, 0, 0, 0);
    #pragma unroll
    for (int j = 0; j < 4; ++j) kf[j] = kn[j];
    #pragma unroll
    for (int j = 0; j < 4; ++j) vf[j] = vn[j];
  }

  // rowsum reduce across the 16 lanes sharing rows (lo dimension)
  #pragma unroll
  for (int m = 1; m < 16; m <<= 1) {
    #pragma unroll
    for (int r = 0; r < 4; ++r) rs[r] += __shfl_xor(rs[r], m, 64);
  }
  float ir[4];
  #pragma unroll
  for (int r = 0; r < 4; ++r) ir[r] = 1.0f / rs[r];

  // write normalized O into Ol[d][q_local] (transpose for coalesced [C][HW] store)
  #pragma unroll
  for (int r = 0; r < 4; ++r) {
    int qcol = wave * 16 + hi * 4 + r;
    Ol[lo * 65 + qcol] = oacc0[r] * ir[r];                        // d = lo (0..15)
    if (lo < 8) Ol[(16 + lo) * 65 + qcol] = oacc1[r] * ir[r];     // d = 16..23
  }
  __syncthreads();
  for (int i2 = tid; i2 < 24 * 64; i2 += 256) {
    int d = i2 >> 6, ql = i2 & 63;
    Y[(size_t)(head * 24 + d) * 4096 + q0 + ql] = Ol[d * 65 + ql];
  }
}

extern "C" void kernel_launch(void* const* d_in, const int* in_sizes, int n_in,
                              void* d_out, int out_size, void* d_ws, size_t ws_size,
                              hipStream_t stream) {
  const float* x      = (const float*)d_in[0];  // [192][4096]
  const float* w_qkv  = (const float*)d_in[1];  // [576][192]
  const float* w_dw   = (const float*)d_in[2];  // [576][9]
  const float* w_proj = (const float*)d_in[3];  // [192][192]
  float* out = (float*)d_out;                   // [192][4096] fp32

  char* ws = (char*)d_ws;
  float* qkv    = (float*)(ws);                 // 576*4096*4 = 9437184
  float* qkvd   = (float*)(ws + 9437184);       // 9437184
  u16*   Qh     = (u16*)  (ws + 18874368);      // 8*4096*32*2 = 2097152
  u16*   Kh     = (u16*)  (ws + 20971520);      // 2097152
  u16*   Vt     = (u16*)  (ws + 23068672);      // 2097152
  float* attn_o = (float*)(ws + 25165824);      // 192*4096*4 = 3145728  (end 28311552)

  gemm192<<<dim3(16, 24), 256, 0, stream>>>(w_qkv, x, qkv);
  dwconv3<<<dim3(9216), 256, 0, stream>>>(qkv, w_dw, qkvd);
  normpack<<<dim3(128), 256, 0, stream>>>(qkvd, Qh, Kh);
  vpack<<<dim3(4096), 256, 0, stream>>>(qkvd, Vt);
  attn<<<dim3(512), 256, 0, stream>>>(Qh, Kh, Vt, attn_o);
  gemm192<<<dim3(16, 8), 256, 0, stream>>>(w_proj, attn_o, out);
}

// Round 2
// 247.248 us; speedup vs baseline: 1.0514x; 1.0514x over previous
//
#include <hip/hip_runtime.h>

typedef unsigned short u16;
typedef unsigned int u32;
typedef short bf16x8 __attribute__((ext_vector_type(8)));
typedef float f32x4 __attribute__((ext_vector_type(4)));

// float -> bf16 bits, round-to-nearest-even (inputs never NaN here)
__device__ __forceinline__ u16 f2bf(float f) {
  union { float f; unsigned int u; } a; a.f = f;
  unsigned int r = a.u + 0x7FFFu + ((a.u >> 16) & 1u);
  return (u16)(r >> 16);
}

// ---- K1/K5: Y[o][p] = sum_c W[o*192+c] * X[c*4096+p]; o-tile = OT rows ----
template <int OT>
__global__ __launch_bounds__(256) void gemm192(const float* __restrict__ W,
                                               const float* __restrict__ X,
                                               float* __restrict__ Y) {
  __shared__ float wlds[OT * 192];
  int tid = threadIdx.x;
  int p = blockIdx.x * 256 + tid;
  int o0 = blockIdx.y * OT;
  for (int i = tid; i < OT * 192; i += 256) wlds[i] = W[o0 * 192 + i];
  __syncthreads();
  float acc[OT];
  #pragma unroll
  for (int i = 0; i < OT; ++i) acc[i] = 0.f;
  for (int c = 0; c < 192; c += 4) {
    float x0 = X[(c + 0) * 4096 + p];
    float x1 = X[(c + 1) * 4096 + p];
    float x2 = X[(c + 2) * 4096 + p];
    float x3 = X[(c + 3) * 4096 + p];
    #pragma unroll
    for (int oo = 0; oo < OT; ++oo) {
      const float4* wv = (const float4*)&wlds[oo * 192 + c];  // broadcast b128
      acc[oo] = fmaf(wv->x, x0, fmaf(wv->y, x1, fmaf(wv->z, x2, fmaf(wv->w, x3, acc[oo]))));
    }
  }
  #pragma unroll
  for (int oo = 0; oo < OT; ++oo) Y[(size_t)(o0 + oo) * 4096 + p] = acc[oo];
}

// ---- K2: depthwise 3x3, pad=1, on [576][64][64] ----
__global__ __launch_bounds__(256) void dwconv3(const float* __restrict__ in,
                                               const float* __restrict__ w,
                                               float* __restrict__ out) {
  int idx = blockIdx.x * 256 + threadIdx.x;  // c*4096 + p
  int c = idx >> 12;
  int p = idx & 4095;
  int y = p >> 6, x = p & 63;
  const float* wc = w + c * 9;
  const float* ic = in + (size_t)c * 4096;
  float s = 0.f;
  #pragma unroll
  for (int i = 0; i < 3; ++i) {
    int yy = y + i - 1;
    if ((unsigned)yy >= 64u) continue;
    #pragma unroll
    for (int j = 0; j < 3; ++j) {
      int xx = x + j - 1;
      if ((unsigned)xx >= 64u) continue;
      s = fmaf(wc[i * 3 + j], ic[yy * 64 + xx], s);
    }
  }
  out[idx] = s;
}

// ---- K3: L2-normalize q,k per (head,pixel); pack bf16 rows [h][p][32] via LDS (coalesced u32 stores)
// SCALE*log2(e) folded into Q so attention uses exp2().
__global__ __launch_bounds__(256) void normpack(const float* __restrict__ qkv,
                                                u32* __restrict__ Qh32,
                                                u32* __restrict__ Kh32) {
  __shared__ u32 Ql[256 * 17];
  __shared__ u32 Kl[256 * 17];
  int tid = threadIdx.x;
  int bid = blockIdx.x;          // 128 blocks
  int h = bid >> 4;
  int p0 = (bid & 15) << 8;
  int p = p0 + tid;
  const float QSC = 0.20412414523193154f * 1.4426950408889634f;  // 24^-0.5 * log2(e)
  float qv[24], kv[24];
  float sq = 0.f, sk = 0.f;
  #pragma unroll
  for (int d = 0; d < 24; ++d) {
    qv[d] = qkv[(size_t)(h * 24 + d) * 4096 + p];
    sq = fmaf(qv[d], qv[d], sq);
  }
  #pragma unroll
  for (int d = 0; d < 24; ++d) {
    kv[d] = qkv[(size_t)(192 + h * 24 + d) * 4096 + p];
    sk = fmaf(kv[d], kv[d], sk);
  }
  float iq = QSC / fmaxf(sqrtf(sq), 1e-12f);  // F.normalize: x / max(||x||, eps)
  float ik = 1.0f / fmaxf(sqrtf(sk), 1e-12f);
  u32* qrow = Ql + tid * 17;
  u32* krow = Kl + tid * 17;
  #pragma unroll
  for (int j = 0; j < 12; ++j) {
    qrow[j] = ((u32)f2bf(qv[2 * j + 1] * iq) << 16) | f2bf(qv[2 * j] * iq);
    krow[j] = ((u32)f2bf(kv[2 * j + 1] * ik) << 16) | f2bf(kv[2 * j] * ik);
  }
  #pragma unroll
  for (int j = 12; j < 16; ++j) { qrow[j] = 0; krow[j] = 0; }
  __syncthreads();
  size_t base = ((size_t)(h << 12) + p0) * 16;
  for (int i = tid; i < 4096; i += 256) {
    u32 li = (i >> 4) * 17 + (i & 15);
    Qh32[base + i] = Ql[li];
    Kh32[base + i] = Kl[li];
  }
}

// ---- K3b: V pack, k-permuted to match P's packed LDS layout. Vt[h][d][k'] bf16.
// k' within each 64-key tile: k' = 2*(m&15) + ((m>>4)&1) + (m&32).
// Row d==24 is all ones -> PV MFMA computes the softmax denominator for free.
__global__ __launch_bounds__(256) void vpack(const float* __restrict__ qkv,
                                             u16* __restrict__ Vt) {
  int idx = blockIdx.x * 256 + threadIdx.x;  // 8*32*4096
  int m = idx & 4095;
  int d = (idx >> 12) & 31;
  int h = idx >> 17;
  int kp = (m & ~63) | (((m & 15) << 1) + ((m >> 4) & 1) + (m & 32));
  u16 val;
  if (d < 24)       val = f2bf(qkv[(size_t)(384 + h * 24 + d) * 4096 + m]);
  else if (d == 24) val = 0x3F80;  // bf16 1.0
  else              val = 0;
  Vt[(((size_t)(h * 32 + d)) << 12) + kp] = val;
}

#define PSTR 36  // dwords per P row (16B-aligned rows, 2-way-free banks)

__device__ __forceinline__ void ldKV(const u16* __restrict__ Kb, const u16* __restrict__ Vb,
                                     int k0, int lo, int hi, bf16x8* kf, bf16x8* vf) {
  #pragma unroll
  for (int j = 0; j < 4; ++j)
    kf[j] = *(const bf16x8*)(Kb + (((size_t)(k0 + j * 16 + lo)) << 5) + hi * 8);
  #pragma unroll
  for (int c = 0; c < 2; ++c)
    #pragma unroll
    for (int n = 0; n < 2; ++n)
      vf[c * 2 + n] = *(const bf16x8*)(Vb + (((size_t)(n * 16 + lo)) << 12) + k0 + c * 32 + hi * 8);
}

// ---- K4: flash attention, K-split by 4. No online max (logits bounded +-0.295 after log2e fold).
// Emits un-normalized partial numerators [ks][h][q][24] and denominators [ks][h][q].
__global__ __launch_bounds__(256) void attn(const u16* __restrict__ Qh,
                                            const u16* __restrict__ Kh,
                                            const u16* __restrict__ Vt,
                                            float* __restrict__ pnum,
                                            float* __restrict__ pden) {
  __shared__ u32 Pl[64 * PSTR];  // 9216 B
  int tid = threadIdx.x;
  int wave = tid >> 6, lane = tid & 63;
  int lo = lane & 15, hi = lane >> 4;
  int b = blockIdx.x;
  int head = b & 7;              // head == XCD (round-robin) -> K/V L2-resident per XCD
  int t = b >> 3;
  int q0 = (t & 63) << 6;
  int ks = t >> 6;               // 0..3
  int kbase = ks << 10;          // 1024 keys per split

  const u16* Kb = Kh + ((size_t)head << 17);
  const u16* Vb = Vt + ((size_t)head << 17);

  bf16x8 qf = *(const bf16x8*)(Qh + (((size_t)(head << 12) + q0 + wave * 16 + lo) << 5) + hi * 8);

  f32x4 o0 = {0.f, 0.f, 0.f, 0.f};
  f32x4 o1 = {0.f, 0.f, 0.f, 0.f};

  u32* Pw = Pl + (wave * 16 + hi * 4) * PSTR + lo;
  const u32* Pr = Pl + (wave * 16 + lo) * PSTR + hi * 4;

  bf16x8 kf[2][4], vf[2][4];
  ldKV(Kb, Vb, kbase, lo, hi, kf[0], vf[0]);

  #pragma unroll
  for (int it = 0; it < 16; ++it) {
    int cur = it & 1;
    if (it < 15) ldKV(Kb, Vb, kbase + (it + 1) * 64, lo, hi, kf[cur ^ 1], vf[cur ^ 1]);

    f32x4 z = {0.f, 0.f, 0.f, 0.f};
    f32x4 s0 = __builtin_amdgcn_mfma_f32_16x16x32_bf16(qf, kf[cur][0], z, 0, 0, 0);
    f32x4 s1 = __builtin_amdgcn_mfma_f32_16x16x32_bf16(qf, kf[cur][1], z, 0, 0, 0);
    f32x4 s2 = __builtin_amdgcn_mfma_f32_16x16x32_bf16(qf, kf[cur][2], z, 0, 0, 0);
    f32x4 s3 = __builtin_amdgcn_mfma_f32_16x16x32_bf16(qf, kf[cur][3], z, 0, 0, 0);

    #pragma unroll
    for (int r = 0; r < 4; ++r) {
      u32 e0 = __float_as_uint(__builtin_amdgcn_exp2f(s0[r]));
      u32 e1 = __float_as_uint(__builtin_amdgcn_exp2f(s1[r]));
      u32 e2 = __float_as_uint(__builtin_amdgcn_exp2f(s2[r]));
      u32 e3 = __float_as_uint(__builtin_amdgcn_exp2f(s3[r]));
      // truncate-to-bf16 pack: low u16 = e0 (k'=2lo), high u16 = e1 (k'=2lo+1)
      Pw[r * PSTR]      = __builtin_amdgcn_perm(e1, e0, 0x07060302u);
      Pw[r * PSTR + 16] = __builtin_amdgcn_perm(e3, e2, 0x07060302u);
    }
    // wave-private LDS round-trip (in-order per wave; verified round 1)
    bf16x8 a0 = *(const bf16x8*)(Pr);
    bf16x8 a1 = *(const bf16x8*)(Pr + 16);
    o0 = __builtin_amdgcn_mfma_f32_16x16x32_bf16(a0, vf[cur][0], o0, 0, 0, 0);
    o1 = __builtin_amdgcn_mfma_f32_16x16x32_bf16(a0, vf[cur][1], o1, 0, 0, 0);
    o0 = __builtin_amdgcn_mfma_f32_16x16x32_bf16(a1, vf[cur][2], o0, 0, 0, 0);
    o1 = __builtin_amdgcn_mfma_f32_16x16x32_bf16(a1, vf[cur][3], o1, 0, 0, 0);
  }

  // epilogue: C-layout direct store. d = lo (o0), 16+lo (o1, lo<8); lo==8 of o1 is the ones-row sum.
  size_t qg = ((size_t)((ks * 8 + head)) << 12) + q0 + wave * 16 + hi * 4;
  #pragma unroll
  for (int r = 0; r < 4; ++r) {
    float* row = pnum + (qg + r) * 24;
    row[lo] = o0[r];
    if (lo < 8) row[16 + lo] = o1[r];
    if (lo == 8) pden[qg + r] = o1[r];
  }
}

// ---- K4b: combine split-K partials -> attn_o [192][4096] ----
__global__ __launch_bounds__(256) void combine(const float* __restrict__ pnum,
                                               const float* __restrict__ pden,
                                               float* __restrict__ Y) {
  int idx = blockIdx.x * 256 + threadIdx.x;  // 8*4096
  int h = idx >> 12, q = idx & 4095;
  float den = 0.f;
  #pragma unroll
  for (int s = 0; s < 4; ++s) den += pden[((size_t)((s * 8 + h)) << 12) + q];
  float inv = 1.0f / den;
  float acc[24];
  #pragma unroll
  for (int d = 0; d < 24; ++d) acc[d] = 0.f;
  #pragma unroll
  for (int s = 0; s < 4; ++s) {
    const float* row = pnum + ((((size_t)((s * 8 + h)) << 12) + q) * 24);
    #pragma unroll
    for (int d = 0; d < 24; ++d) acc[d] += row[d];
  }
  #pragma unroll
  for (int d = 0; d < 24; ++d) Y[(size_t)(h * 24 + d) * 4096 + q] = acc[d] * inv;
}

extern "C" void kernel_launch(void* const* d_in, const int* in_sizes, int n_in,
                              void* d_out, int out_size, void* d_ws, size_t ws_size,
                              hipStream_t stream) {
  const float* x      = (const float*)d_in[0];  // [192][4096]
  const float* w_qkv  = (const float*)d_in[1];  // [576][192]
  const float* w_dw   = (const float*)d_in[2];  // [576][9]
  const float* w_proj = (const float*)d_in[3];  // [192][192]
  float* out = (float*)d_out;                   // [192][4096] fp32

  char* ws = (char*)d_ws;
  float* qkv    = (float*)(ws);                 // 9437184           (dead after dwconv3)
  float* qkvd   = (float*)(ws + 9437184);       // 9437184           (dead after vpack)
  u16*   Qh     = (u16*)  (ws + 18874368);      // 2097152
  u16*   Kh     = (u16*)  (ws + 20971520);      // 2097152
  u16*   Vt     = (u16*)  (ws + 23068672);      // 2097152  (end 25165824)
  // reuse the qkv/qkvd region for attention outputs (both dead by then):
  float* pnum   = (float*)(ws);                 // 4*8*4096*24*4 = 12582912
  float* pden   = (float*)(ws + 12582912);      // 4*8*4096*4  = 524288
  float* attn_o = (float*)(ws + 13107200);      // 192*4096*4  = 3145728 (end 16252928)

  gemm192<24><<<dim3(16, 24), 256, 0, stream>>>(w_qkv, x, qkv);
  dwconv3<<<dim3(9216), 256, 0, stream>>>(qkv, w_dw, qkvd);
  normpack<<<dim3(128), 256, 0, stream>>>(qkvd, (u32*)Qh, (u32*)Kh);
  vpack<<<dim3(4096), 256, 0, stream>>>(qkvd, Vt);
  attn<<<dim3(2048), 256, 0, stream>>>(Qh, Kh, Vt, pnum, pden);
  combine<<<dim3(128), 256, 0, stream>>>(pnum, pden, attn_o);
  gemm192<12><<<dim3(16, 16), 256, 0, stream>>>(w_proj, attn_o, out);
}

// Round 3
// 220.727 us; speedup vs baseline: 1.1777x; 1.1202x over previous
//
#include <hip/hip_runtime.h>

typedef unsigned short u16;
typedef unsigned int u32;
typedef short bf16x8 __attribute__((ext_vector_type(8)));
typedef float f32x4 __attribute__((ext_vector_type(4)));

// float -> bf16 bits, round-to-nearest-even (inputs never NaN here)
__device__ __forceinline__ u16 f2bf(float f) {
  union { float f; unsigned int u; } a; a.f = f;
  unsigned int r = a.u + 0x7FFFu + ((a.u >> 16) & 1u);
  return (u16)(r >> 16);
}

// ---- K1/K5: Y[o][p] = sum_c W[o*192+c] * X[c*4096+p]; o-tile = OT rows ----
template <int OT>
__global__ __launch_bounds__(256) void gemm192(const float* __restrict__ W,
                                               const float* __restrict__ X,
                                               float* __restrict__ Y) {
  __shared__ float wlds[OT * 192];
  int tid = threadIdx.x;
  int p = blockIdx.x * 256 + tid;
  int o0 = blockIdx.y * OT;
  for (int i = tid; i < OT * 192; i += 256) wlds[i] = W[o0 * 192 + i];
  __syncthreads();
  float acc[OT];
  #pragma unroll
  for (int i = 0; i < OT; ++i) acc[i] = 0.f;
  for (int c = 0; c < 192; c += 4) {
    float x0 = X[(c + 0) * 4096 + p];
    float x1 = X[(c + 1) * 4096 + p];
    float x2 = X[(c + 2) * 4096 + p];
    float x3 = X[(c + 3) * 4096 + p];
    #pragma unroll
    for (int oo = 0; oo < OT; ++oo) {
      const float4* wv = (const float4*)&wlds[oo * 192 + c];  // broadcast b128
      acc[oo] = fmaf(wv->x, x0, fmaf(wv->y, x1, fmaf(wv->z, x2, fmaf(wv->w, x3, acc[oo]))));
    }
  }
  #pragma unroll
  for (int oo = 0; oo < OT; ++oo) Y[(size_t)(o0 + oo) * 4096 + p] = acc[oo];
}

// ---- K2: depthwise 3x3, pad=1, on [576][64][64] ----
__global__ __launch_bounds__(256) void dwconv3(const float* __restrict__ in,
                                               const float* __restrict__ w,
                                               float* __restrict__ out) {
  int idx = blockIdx.x * 256 + threadIdx.x;  // c*4096 + p
  int c = idx >> 12;
  int p = idx & 4095;
  int y = p >> 6, x = p & 63;
  const float* wc = w + c * 9;
  const float* ic = in + (size_t)c * 4096;
  float s = 0.f;
  #pragma unroll
  for (int i = 0; i < 3; ++i) {
    int yy = y + i - 1;
    if ((unsigned)yy >= 64u) continue;
    #pragma unroll
    for (int j = 0; j < 3; ++j) {
      int xx = x + j - 1;
      if ((unsigned)xx >= 64u) continue;
      s = fmaf(wc[i * 3 + j], ic[yy * 64 + xx], s);
    }
  }
  out[idx] = s;
}

// ---- K3: fused normalize+pack for Q,K (bf16 rows [h][p][32]) and V (k-permuted [h][d][k']).
// SCALE*log2(e) folded into Q. V row d==24 is ones -> PV MFMA yields softmax denominator.
__global__ __launch_bounds__(256) void nvpack(const float* __restrict__ qkv,
                                              u32* __restrict__ Qh32,
                                              u32* __restrict__ Kh32,
                                              u32* __restrict__ Vt32) {
  __shared__ u32 Ql[256 * 17];
  __shared__ u32 Kl[256 * 17];
  __shared__ u16 Vl[32 * 256];
  int tid = threadIdx.x;
  int bid = blockIdx.x;          // 128 blocks
  int h = bid >> 4;
  int p0 = (bid & 15) << 8;
  int p = p0 + tid;
  const float QSC = 0.20412414523193154f * 1.4426950408889634f;  // 24^-0.5 * log2(e)
  float qv[24], kv[24], vv[24];
  float sq = 0.f, sk = 0.f;
  #pragma unroll
  for (int d = 0; d < 24; ++d) {
    qv[d] = qkv[(size_t)(h * 24 + d) * 4096 + p];
    sq = fmaf(qv[d], qv[d], sq);
  }
  #pragma unroll
  for (int d = 0; d < 24; ++d) {
    kv[d] = qkv[(size_t)(192 + h * 24 + d) * 4096 + p];
    sk = fmaf(kv[d], kv[d], sk);
  }
  #pragma unroll
  for (int d = 0; d < 24; ++d) vv[d] = qkv[(size_t)(384 + h * 24 + d) * 4096 + p];
  float iq = QSC / fmaxf(sqrtf(sq), 1e-12f);  // F.normalize: x / max(||x||, eps)
  float ik = 1.0f / fmaxf(sqrtf(sk), 1e-12f);
  u32* qrow = Ql + tid * 17;
  u32* krow = Kl + tid * 17;
  #pragma unroll
  for (int j = 0; j < 12; ++j) {
    qrow[j] = ((u32)f2bf(qv[2 * j + 1] * iq) << 16) | f2bf(qv[2 * j] * iq);
    krow[j] = ((u32)f2bf(kv[2 * j + 1] * ik) << 16) | f2bf(kv[2 * j] * ik);
  }
  #pragma unroll
  for (int j = 12; j < 16; ++j) { qrow[j] = 0; krow[j] = 0; }
  // V: scatter into LDS with the within-64 k-permutation, then coalesced store
  int kp = (tid & ~63) | (((tid & 15) << 1) + ((tid >> 4) & 1) + (tid & 32));
  #pragma unroll
  for (int d = 0; d < 24; ++d) Vl[d * 256 + kp] = f2bf(vv[d]);
  Vl[24 * 256 + kp] = 0x3F80;  // bf16 1.0
  u32* Vl32 = (u32*)Vl;
  for (int i = tid; i < 7 * 128; i += 256) Vl32[25 * 128 + i] = 0;
  __syncthreads();
  size_t base = ((size_t)(h << 12) + p0) * 16;
  for (int i = tid; i < 4096; i += 256) {
    u32 li = (i >> 4) * 17 + (i & 15);
    Qh32[base + i] = Ql[li];
    Kh32[base + i] = Kl[li];
  }
  for (int i = tid; i < 4096; i += 256) {
    int d = i >> 7, c = i & 127;
    Vt32[(((size_t)(h * 32 + d)) << 11) + (p0 >> 1) + c] = Vl32[i];
  }
}

#define PSTR 36  // dwords per P row (16B-aligned rows)

// ---- K4: flash attention, 128 queries/block (2 frags/wave), split-K 4, no barriers.
// No online max (logits bounded). Partial numerators [ks][h][q][24], denominators [ks][h][q].
__global__ __launch_bounds__(256, 4) void attn(const u16* __restrict__ Qh,
                                               const u16* __restrict__ Kh,
                                               const u16* __restrict__ Vt,
                                               float* __restrict__ pnum,
                                               float* __restrict__ pden) {
  __shared__ u32 Pl[2][128 * PSTR];  // parity double-buffer, 36864 B
  int tid = threadIdx.x;
  int wave = tid >> 6, lane = tid & 63;
  int lo = lane & 15, hi = lane >> 4;
  int b = blockIdx.x;
  int head = b & 7;              // head == XCD (round-robin) -> K/V L2-resident per XCD
  int t = b >> 3;
  int q0 = (t & 31) << 7;        // 32 q-tiles of 128
  int ks = t >> 5;               // 0..3
  int kbase = ks << 10;          // 1024 keys per split

  const u16* Kb = Kh + ((size_t)head << 17);
  const u16* Vb = Vt + ((size_t)head << 17);

  size_t qbase = ((size_t)(head << 12) + q0 + wave * 32 + lo) << 5;
  bf16x8 qf0 = *(const bf16x8*)(Qh + qbase + hi * 8);
  bf16x8 qf1 = *(const bf16x8*)(Qh + qbase + (16 << 5) + hi * 8);

  f32x4 o00 = {0.f, 0.f, 0.f, 0.f}, o01 = o00, o10 = o00, o11 = o00;

  int wr0 = (wave * 32 + hi * 4) * PSTR + lo;   // frag0 write base (dwords)
  int rd0 = (wave * 32 + lo) * PSTR + hi * 4;   // frag0 read base (dwords)

  bf16x8 kf[2][4];
  #pragma unroll
  for (int j = 0; j < 4; ++j)
    kf[0][j] = *(const bf16x8*)(Kb + (((size_t)(kbase + j * 16 + lo)) << 5) + hi * 8);

  #pragma unroll
  for (int it = 0; it < 16; ++it) {
    int cur = it & 1;
    int k0 = kbase + it * 64;
    // V for CURRENT iter (consumed at bottom, ~full body of latency cover)
    bf16x8 vf[4];
    #pragma unroll
    for (int c = 0; c < 2; ++c)
      #pragma unroll
      for (int n = 0; n < 2; ++n)
        vf[c * 2 + n] = *(const bf16x8*)(Vb + (((size_t)(n * 16 + lo)) << 12) + k0 + c * 32 + hi * 8);
    // K for NEXT iter
    if (it < 15) {
      #pragma unroll
      for (int j = 0; j < 4; ++j)
        kf[cur ^ 1][j] = *(const bf16x8*)(Kb + (((size_t)(k0 + 64 + j * 16 + lo)) << 5) + hi * 8);
    }

    f32x4 z = {0.f, 0.f, 0.f, 0.f};
    f32x4 s00 = __builtin_amdgcn_mfma_f32_16x16x32_bf16(qf0, kf[cur][0], z, 0, 0, 0);
    f32x4 s01 = __builtin_amdgcn_mfma_f32_16x16x32_bf16(qf0, kf[cur][1], z, 0, 0, 0);
    f32x4 s02 = __builtin_amdgcn_mfma_f32_16x16x32_bf16(qf0, kf[cur][2], z, 0, 0, 0);
    f32x4 s03 = __builtin_amdgcn_mfma_f32_16x16x32_bf16(qf0, kf[cur][3], z, 0, 0, 0);
    f32x4 s10 = __builtin_amdgcn_mfma_f32_16x16x32_bf16(qf1, kf[cur][0], z, 0, 0, 0);
    f32x4 s11 = __builtin_amdgcn_mfma_f32_16x16x32_bf16(qf1, kf[cur][1], z, 0, 0, 0);
    f32x4 s12 = __builtin_amdgcn_mfma_f32_16x16x32_bf16(qf1, kf[cur][2], z, 0, 0, 0);
    f32x4 s13 = __builtin_amdgcn_mfma_f32_16x16x32_bf16(qf1, kf[cur][3], z, 0, 0, 0);

    u32* PW = &Pl[cur][0];
    const u32* PR = &Pl[cur][0];
    // frag0: exp + truncate-pack + LDS write, then read (latency covered by frag1 work)
    #pragma unroll
    for (int r = 0; r < 4; ++r) {
      u32 e0 = __float_as_uint(__builtin_amdgcn_exp2f(s00[r]));
      u32 e1 = __float_as_uint(__builtin_amdgcn_exp2f(s01[r]));
      u32 e2 = __float_as_uint(__builtin_amdgcn_exp2f(s02[r]));
      u32 e3 = __float_as_uint(__builtin_amdgcn_exp2f(s03[r]));
      PW[wr0 + r * PSTR]      = __builtin_amdgcn_perm(e1, e0, 0x07060302u);
      PW[wr0 + r * PSTR + 16] = __builtin_amdgcn_perm(e3, e2, 0x07060302u);
    }
    bf16x8 a00 = *(const bf16x8*)(PR + rd0);
    bf16x8 a01 = *(const bf16x8*)(PR + rd0 + 16);
    // frag1
    #pragma unroll
    for (int r = 0; r < 4; ++r) {
      u32 e0 = __float_as_uint(__builtin_amdgcn_exp2f(s10[r]));
      u32 e1 = __float_as_uint(__builtin_amdgcn_exp2f(s11[r]));
      u32 e2 = __float_as_uint(__builtin_amdgcn_exp2f(s12[r]));
      u32 e3 = __float_as_uint(__builtin_amdgcn_exp2f(s13[r]));
      PW[wr0 + 16 * PSTR + r * PSTR]      = __builtin_amdgcn_perm(e1, e0, 0x07060302u);
      PW[wr0 + 16 * PSTR + r * PSTR + 16] = __builtin_amdgcn_perm(e3, e2, 0x07060302u);
    }
    bf16x8 a10 = *(const bf16x8*)(PR + rd0 + 16 * PSTR);
    bf16x8 a11 = *(const bf16x8*)(PR + rd0 + 16 * PSTR + 16);

    o00 = __builtin_amdgcn_mfma_f32_16x16x32_bf16(a00, vf[0], o00, 0, 0, 0);
    o01 = __builtin_amdgcn_mfma_f32_16x16x32_bf16(a00, vf[1], o01, 0, 0, 0);
    o10 = __builtin_amdgcn_mfma_f32_16x16x32_bf16(a10, vf[0], o10, 0, 0, 0);
    o11 = __builtin_amdgcn_mfma_f32_16x16x32_bf16(a10, vf[1], o11, 0, 0, 0);
    o00 = __builtin_amdgcn_mfma_f32_16x16x32_bf16(a01, vf[2], o00, 0, 0, 0);
    o01 = __builtin_amdgcn_mfma_f32_16x16x32_bf16(a01, vf[3], o01, 0, 0, 0);
    o10 = __builtin_amdgcn_mfma_f32_16x16x32_bf16(a11, vf[2], o10, 0, 0, 0);
    o11 = __builtin_amdgcn_mfma_f32_16x16x32_bf16(a11, vf[3], o11, 0, 0, 0);
  }

  // epilogue: C-layout direct store. d = lo (o*0), 16+lo (o*1, lo<8); lo==8 of o*1 is ones-row sum.
  size_t qg = ((size_t)(ks * 8 + head) << 12) + q0 + wave * 32 + hi * 4;
  #pragma unroll
  for (int r = 0; r < 4; ++r) {
    float* row0 = pnum + (qg + r) * 24;
    row0[lo] = o00[r];
    if (lo < 8) row0[16 + lo] = o01[r];
    if (lo == 8) pden[qg + r] = o01[r];
    float* row1 = pnum + (qg + 16 + r) * 24;
    row1[lo] = o10[r];
    if (lo < 8) row1[16 + lo] = o11[r];
    if (lo == 8) pden[qg + 16 + r] = o11[r];
  }
}

// ---- K4b: combine split-K partials -> attn_o [192][4096] ----
__global__ __launch_bounds__(256) void combine(const float* __restrict__ pnum,
                                               const float* __restrict__ pden,
                                               float* __restrict__ Y) {
  int idx = blockIdx.x * 256 + threadIdx.x;  // 8*4096
  int h = idx >> 12, q = idx & 4095;
  float den = 0.f;
  #pragma unroll
  for (int s = 0; s < 4; ++s) den += pden[((size_t)(s * 8 + h) << 12) + q];
  float inv = 1.0f / den;
  float acc[24];
  #pragma unroll
  for (int d = 0; d < 24; ++d) acc[d] = 0.f;
  #pragma unroll
  for (int s = 0; s < 4; ++s) {
    const float* row = pnum + ((((size_t)(s * 8 + h) << 12) + q) * 24);
    #pragma unroll
    for (int d = 0; d < 24; ++d) acc[d] += row[d];
  }
  #pragma unroll
  for (int d = 0; d < 24; ++d) Y[(size_t)(h * 24 + d) * 4096 + q] = acc[d] * inv;
}

extern "C" void kernel_launch(void* const* d_in, const int* in_sizes, int n_in,
                              void* d_out, int out_size, void* d_ws, size_t ws_size,
                              hipStream_t stream) {
  const float* x      = (const float*)d_in[0];  // [192][4096]
  const float* w_qkv  = (const float*)d_in[1];  // [576][192]
  const float* w_dw   = (const float*)d_in[2];  // [576][9]
  const float* w_proj = (const float*)d_in[3];  // [192][192]
  float* out = (float*)d_out;                   // [192][4096] fp32

  char* ws = (char*)d_ws;
  float* qkv    = (float*)(ws);                 // 9437184           (dead after dwconv3)
  float* qkvd   = (float*)(ws + 9437184);       // 9437184           (dead after nvpack)
  u16*   Qh     = (u16*)  (ws + 18874368);      // 2097152
  u16*   Kh     = (u16*)  (ws + 20971520);      // 2097152
  u16*   Vt     = (u16*)  (ws + 23068672);      // 2097152  (end 25165824)
  // reuse the qkv/qkvd region for attention outputs (both dead by then):
  float* pnum   = (float*)(ws);                 // 4*8*4096*24*4 = 12582912
  float* pden   = (float*)(ws + 12582912);      // 4*8*4096*4  = 524288
  float* attn_o = (float*)(ws + 13107200);      // 192*4096*4  = 3145728 (end 16252928)

  gemm192<36><<<dim3(16, 16), 256, 0, stream>>>(w_qkv, x, qkv);
  dwconv3<<<dim3(9216), 256, 0, stream>>>(qkv, w_dw, qkvd);
  nvpack<<<dim3(128), 256, 0, stream>>>(qkvd, (u32*)Qh, (u32*)Kh, (u32*)Vt);
  attn<<<dim3(1024), 256, 0, stream>>>(Qh, Kh, Vt, pnum, pden);
  combine<<<dim3(128), 256, 0, stream>>>(pnum, pden, attn_o);
  gemm192<12><<<dim3(16, 16), 256, 0, stream>>>(w_proj, attn_o, out);
}

// Round 4
// 181.820 us; speedup vs baseline: 1.4297x; 1.2140x over previous
//
#include <hip/hip_runtime.h>

typedef unsigned short u16;
typedef unsigned int u32;
typedef short bf16x8 __attribute__((ext_vector_type(8)));
typedef float f32x4 __attribute__((ext_vector_type(4)));

// float -> bf16 bits, round-to-nearest-even (inputs never NaN here)
__device__ __forceinline__ u16 f2bf(float f) {
  union { float f; unsigned int u; } a; a.f = f;
  unsigned int r = a.u + 0x7FFFu + ((a.u >> 16) & 1u);
  return (u16)(r >> 16);
}

// ---- K1/K5: Y[o][p] = sum_c W[o*192+c] * X[c*4096+p]; o-tile = OT rows ----
// OT sized for occupancy: grid_y = (M/OT); keep >= 2 blocks/CU resident.
template <int OT>
__global__ __launch_bounds__(256) void gemm192(const float* __restrict__ W,
                                               const float* __restrict__ X,
                                               float* __restrict__ Y) {
  __shared__ float wlds[OT * 192];
  int tid = threadIdx.x;
  int p = blockIdx.x * 256 + tid;
  int o0 = blockIdx.y * OT;
  for (int i = tid; i < OT * 192; i += 256) wlds[i] = W[o0 * 192 + i];
  __syncthreads();
  float acc[OT];
  #pragma unroll
  for (int i = 0; i < OT; ++i) acc[i] = 0.f;
  // software-pipelined: X loads for c+4 issued before FMAs of c
  float x0 = X[0 * 4096 + p];
  float x1 = X[1 * 4096 + p];
  float x2 = X[2 * 4096 + p];
  float x3 = X[3 * 4096 + p];
  for (int c = 0; c < 192; c += 4) {
    float n0, n1, n2, n3;
    if (c < 188) {
      n0 = X[(c + 4) * 4096 + p];
      n1 = X[(c + 5) * 4096 + p];
      n2 = X[(c + 6) * 4096 + p];
      n3 = X[(c + 7) * 4096 + p];
    }
    #pragma unroll
    for (int oo = 0; oo < OT; ++oo) {
      const float4* wv = (const float4*)&wlds[oo * 192 + c];  // broadcast b128
      acc[oo] = fmaf(wv->x, x0, fmaf(wv->y, x1, fmaf(wv->z, x2, fmaf(wv->w, x3, acc[oo]))));
    }
    x0 = n0; x1 = n1; x2 = n2; x3 = n3;
  }
  #pragma unroll
  for (int oo = 0; oo < OT; ++oo) Y[(size_t)(o0 + oo) * 4096 + p] = acc[oo];
}

// ---- K2: depthwise 3x3, pad=1, on [576][64][64] ----
__global__ __launch_bounds__(256) void dwconv3(const float* __restrict__ in,
                                               const float* __restrict__ w,
                                               float* __restrict__ out) {
  int idx = blockIdx.x * 256 + threadIdx.x;  // c*4096 + p
  int c = idx >> 12;
  int p = idx & 4095;
  int y = p >> 6, x = p & 63;
  const float* wc = w + c * 9;
  const float* ic = in + (size_t)c * 4096;
  float s = 0.f;
  #pragma unroll
  for (int i = 0; i < 3; ++i) {
    int yy = y + i - 1;
    if ((unsigned)yy >= 64u) continue;
    #pragma unroll
    for (int j = 0; j < 3; ++j) {
      int xx = x + j - 1;
      if ((unsigned)xx >= 64u) continue;
      s = fmaf(wc[i * 3 + j], ic[yy * 64 + xx], s);
    }
  }
  out[idx] = s;
}

// ---- K3: fused normalize+pack for Q,K (bf16 rows [h][p][32]) and V (k-permuted [h][d][k']).
// SCALE*log2(e) folded into Q. V row d==24 is ones -> PV MFMA yields softmax denominator.
__global__ __launch_bounds__(256) void nvpack(const float* __restrict__ qkv,
                                              u32* __restrict__ Qh32,
                                              u32* __restrict__ Kh32,
                                              u32* __restrict__ Vt32) {
  __shared__ u32 Ql[256 * 17];
  __shared__ u32 Kl[256 * 17];
  __shared__ u16 Vl[32 * 256];
  int tid = threadIdx.x;
  int bid = blockIdx.x;          // 128 blocks
  int h = bid >> 4;
  int p0 = (bid & 15) << 8;
  int p = p0 + tid;
  const float QSC = 0.20412414523193154f * 1.4426950408889634f;  // 24^-0.5 * log2(e)
  float qv[24], kv[24], vv[24];
  float sq = 0.f, sk = 0.f;
  #pragma unroll
  for (int d = 0; d < 24; ++d) {
    qv[d] = qkv[(size_t)(h * 24 + d) * 4096 + p];
    sq = fmaf(qv[d], qv[d], sq);
  }
  #pragma unroll
  for (int d = 0; d < 24; ++d) {
    kv[d] = qkv[(size_t)(192 + h * 24 + d) * 4096 + p];
    sk = fmaf(kv[d], kv[d], sk);
  }
  #pragma unroll
  for (int d = 0; d < 24; ++d) vv[d] = qkv[(size_t)(384 + h * 24 + d) * 4096 + p];
  float iq = QSC / fmaxf(sqrtf(sq), 1e-12f);  // F.normalize: x / max(||x||, eps)
  float ik = 1.0f / fmaxf(sqrtf(sk), 1e-12f);
  u32* qrow = Ql + tid * 17;
  u32* krow = Kl + tid * 17;
  #pragma unroll
  for (int j = 0; j < 12; ++j) {
    qrow[j] = ((u32)f2bf(qv[2 * j + 1] * iq) << 16) | f2bf(qv[2 * j] * iq);
    krow[j] = ((u32)f2bf(kv[2 * j + 1] * ik) << 16) | f2bf(kv[2 * j] * ik);
  }
  #pragma unroll
  for (int j = 12; j < 16; ++j) { qrow[j] = 0; krow[j] = 0; }
  // V: scatter into LDS with the within-64 k-permutation, then coalesced store
  int kp = (tid & ~63) | (((tid & 15) << 1) + ((tid >> 4) & 1) + (tid & 32));
  #pragma unroll
  for (int d = 0; d < 24; ++d) Vl[d * 256 + kp] = f2bf(vv[d]);
  Vl[24 * 256 + kp] = 0x3F80;  // bf16 1.0
  u32* Vl32 = (u32*)Vl;
  for (int i = tid; i < 7 * 128; i += 256) Vl32[25 * 128 + i] = 0;
  __syncthreads();
  size_t base = ((size_t)(h << 12) + p0) * 16;
  for (int i = tid; i < 4096; i += 256) {
    u32 li = (i >> 4) * 17 + (i & 15);
    Qh32[base + i] = Ql[li];
    Kh32[base + i] = Kl[li];
  }
  for (int i = tid; i < 4096; i += 256) {
    int d = i >> 7, c = i & 127;
    Vt32[(((size_t)(h * 32 + d)) << 11) + (p0 >> 1) + c] = Vl32[i];
  }
}

#define PSTR 36  // dwords per P row (16B-aligned rows)

// ---- K4: flash attention, 128 queries/block (2 frags/wave), split-K 4, no barriers.
// No online max (logits bounded). Partial numerators [ks][h][q][24], denominators [ks][h][q].
__global__ __launch_bounds__(256, 4) void attn(const u16* __restrict__ Qh,
                                               const u16* __restrict__ Kh,
                                               const u16* __restrict__ Vt,
                                               float* __restrict__ pnum,
                                               float* __restrict__ pden) {
  __shared__ u32 Pl[2][128 * PSTR];  // parity double-buffer, 36864 B
  int tid = threadIdx.x;
  int wave = tid >> 6, lane = tid & 63;
  int lo = lane & 15, hi = lane >> 4;
  int b = blockIdx.x;
  int head = b & 7;              // head == XCD (round-robin) -> K/V L2-resident per XCD
  int t = b >> 3;
  int q0 = (t & 31) << 7;        // 32 q-tiles of 128
  int ks = t >> 5;               // 0..3
  int kbase = ks << 10;          // 1024 keys per split

  const u16* Kb = Kh + ((size_t)head << 17);
  const u16* Vb = Vt + ((size_t)head << 17);

  size_t qbase = ((size_t)(head << 12) + q0 + wave * 32 + lo) << 5;
  bf16x8 qf0 = *(const bf16x8*)(Qh + qbase + hi * 8);
  bf16x8 qf1 = *(const bf16x8*)(Qh + qbase + (16 << 5) + hi * 8);

  f32x4 o00 = {0.f, 0.f, 0.f, 0.f}, o01 = o00, o10 = o00, o11 = o00;

  int wr0 = (wave * 32 + hi * 4) * PSTR + lo;   // frag0 write base (dwords)
  int rd0 = (wave * 32 + lo) * PSTR + hi * 4;   // frag0 read base (dwords)

  bf16x8 kf[2][4];
  #pragma unroll
  for (int j = 0; j < 4; ++j)
    kf[0][j] = *(const bf16x8*)(Kb + (((size_t)(kbase + j * 16 + lo)) << 5) + hi * 8);

  #pragma unroll
  for (int it = 0; it < 16; ++it) {
    int cur = it & 1;
    int k0 = kbase + it * 64;
    // V for CURRENT iter (consumed at bottom, ~full body of latency cover)
    bf16x8 vf[4];
    #pragma unroll
    for (int c = 0; c < 2; ++c)
      #pragma unroll
      for (int n = 0; n < 2; ++n)
        vf[c * 2 + n] = *(const bf16x8*)(Vb + (((size_t)(n * 16 + lo)) << 12) + k0 + c * 32 + hi * 8);
    // K for NEXT iter
    if (it < 15) {
      #pragma unroll
      for (int j = 0; j < 4; ++j)
        kf[cur ^ 1][j] = *(const bf16x8*)(Kb + (((size_t)(k0 + 64 + j * 16 + lo)) << 5) + hi * 8);
    }

    f32x4 z = {0.f, 0.f, 0.f, 0.f};
    f32x4 s00 = __builtin_amdgcn_mfma_f32_16x16x32_bf16(qf0, kf[cur][0], z, 0, 0, 0);
    f32x4 s01 = __builtin_amdgcn_mfma_f32_16x16x32_bf16(qf0, kf[cur][1], z, 0, 0, 0);
    f32x4 s02 = __builtin_amdgcn_mfma_f32_16x16x32_bf16(qf0, kf[cur][2], z, 0, 0, 0);
    f32x4 s03 = __builtin_amdgcn_mfma_f32_16x16x32_bf16(qf0, kf[cur][3], z, 0, 0, 0);
    f32x4 s10 = __builtin_amdgcn_mfma_f32_16x16x32_bf16(qf1, kf[cur][0], z, 0, 0, 0);
    f32x4 s11 = __builtin_amdgcn_mfma_f32_16x16x32_bf16(qf1, kf[cur][1], z, 0, 0, 0);
    f32x4 s12 = __builtin_amdgcn_mfma_f32_16x16x32_bf16(qf1, kf[cur][2], z, 0, 0, 0);
    f32x4 s13 = __builtin_amdgcn_mfma_f32_16x16x32_bf16(qf1, kf[cur][3], z, 0, 0, 0);

    u32* PW = &Pl[cur][0];
    const u32* PR = &Pl[cur][0];
    // frag0: exp + truncate-pack + LDS write, then read (latency covered by frag1 work)
    #pragma unroll
    for (int r = 0; r < 4; ++r) {
      u32 e0 = __float_as_uint(__builtin_amdgcn_exp2f(s00[r]));
      u32 e1 = __float_as_uint(__builtin_amdgcn_exp2f(s01[r]));
      u32 e2 = __float_as_uint(__builtin_amdgcn_exp2f(s02[r]));
      u32 e3 = __float_as_uint(__builtin_amdgcn_exp2f(s03[r]));
      PW[wr0 + r * PSTR]      = __builtin_amdgcn_perm(e1, e0, 0x07060302u);
      PW[wr0 + r * PSTR + 16] = __builtin_amdgcn_perm(e3, e2, 0x07060302u);
    }
    bf16x8 a00 = *(const bf16x8*)(PR + rd0);
    bf16x8 a01 = *(const bf16x8*)(PR + rd0 + 16);
    // frag1
    #pragma unroll
    for (int r = 0; r < 4; ++r) {
      u32 e0 = __float_as_uint(__builtin_amdgcn_exp2f(s10[r]));
      u32 e1 = __float_as_uint(__builtin_amdgcn_exp2f(s11[r]));
      u32 e2 = __float_as_uint(__builtin_amdgcn_exp2f(s12[r]));
      u32 e3 = __float_as_uint(__builtin_amdgcn_exp2f(s13[r]));
      PW[wr0 + 16 * PSTR + r * PSTR]      = __builtin_amdgcn_perm(e1, e0, 0x07060302u);
      PW[wr0 + 16 * PSTR + r * PSTR + 16] = __builtin_amdgcn_perm(e3, e2, 0x07060302u);
    }
    bf16x8 a10 = *(const bf16x8*)(PR + rd0 + 16 * PSTR);
    bf16x8 a11 = *(const bf16x8*)(PR + rd0 + 16 * PSTR + 16);

    o00 = __builtin_amdgcn_mfma_f32_16x16x32_bf16(a00, vf[0], o00, 0, 0, 0);
    o01 = __builtin_amdgcn_mfma_f32_16x16x32_bf16(a00, vf[1], o01, 0, 0, 0);
    o10 = __builtin_amdgcn_mfma_f32_16x16x32_bf16(a10, vf[0], o10, 0, 0, 0);
    o11 = __builtin_amdgcn_mfma_f32_16x16x32_bf16(a10, vf[1], o11, 0, 0, 0);
    o00 = __builtin_amdgcn_mfma_f32_16x16x32_bf16(a01, vf[2], o00, 0, 0, 0);
    o01 = __builtin_amdgcn_mfma_f32_16x16x32_bf16(a01, vf[3], o01, 0, 0, 0);
    o10 = __builtin_amdgcn_mfma_f32_16x16x32_bf16(a11, vf[2], o10, 0, 0, 0);
    o11 = __builtin_amdgcn_mfma_f32_16x16x32_bf16(a11, vf[3], o11, 0, 0, 0);
  }

  // epilogue: C-layout direct store. d = lo (o*0), 16+lo (o*1, lo<8); lo==8 of o*1 is ones-row sum.
  size_t qg = ((size_t)(ks * 8 + head) << 12) + q0 + wave * 32 + hi * 4;
  #pragma unroll
  for (int r = 0; r < 4; ++r) {
    float* row0 = pnum + (qg + r) * 24;
    row0[lo] = o00[r];
    if (lo < 8) row0[16 + lo] = o01[r];
    if (lo == 8) pden[qg + r] = o01[r];
    float* row1 = pnum + (qg + 16 + r) * 24;
    row1[lo] = o10[r];
    if (lo < 8) row1[16 + lo] = o11[r];
    if (lo == 8) pden[qg + 16 + r] = o11[r];
  }
}

// ---- K4b: combine split-K partials -> attn_o [192][4096] ----
__global__ __launch_bounds__(256) void combine(const float* __restrict__ pnum,
                                               const float* __restrict__ pden,
                                               float* __restrict__ Y) {
  int idx = blockIdx.x * 256 + threadIdx.x;  // 8*4096
  int h = idx >> 12, q = idx & 4095;
  float den = 0.f;
  #pragma unroll
  for (int s = 0; s < 4; ++s) den += pden[((size_t)(s * 8 + h) << 12) + q];
  float inv = 1.0f / den;
  float acc[24];
  #pragma unroll
  for (int d = 0; d < 24; ++d) acc[d] = 0.f;
  #pragma unroll
  for (int s = 0; s < 4; ++s) {
    const float* row = pnum + ((((size_t)(s * 8 + h) << 12) + q) * 24);
    #pragma unroll
    for (int d = 0; d < 24; ++d) acc[d] += row[d];
  }
  #pragma unroll
  for (int d = 0; d < 24; ++d) Y[(size_t)(h * 24 + d) * 4096 + q] = acc[d] * inv;
}

extern "C" void kernel_launch(void* const* d_in, const int* in_sizes, int n_in,
                              void* d_out, int out_size, void* d_ws, size_t ws_size,
                              hipStream_t stream) {
  const float* x      = (const float*)d_in[0];  // [192][4096]
  const float* w_qkv  = (const float*)d_in[1];  // [576][192]
  const float* w_dw   = (const float*)d_in[2];  // [576][9]
  const float* w_proj = (const float*)d_in[3];  // [192][192]
  float* out = (float*)d_out;                   // [192][4096] fp32

  char* ws = (char*)d_ws;
  float* qkv    = (float*)(ws);                 // 9437184           (dead after dwconv3)
  float* qkvd   = (float*)(ws + 9437184);       // 9437184           (dead after nvpack)
  u16*   Qh     = (u16*)  (ws + 18874368);      // 2097152
  u16*   Kh     = (u16*)  (ws + 20971520);      // 2097152
  u16*   Vt     = (u16*)  (ws + 23068672);      // 2097152  (end 25165824)
  // reuse the qkv/qkvd region for attention outputs (both dead by then):
  float* pnum   = (float*)(ws);                 // 4*8*4096*24*4 = 12582912
  float* pden   = (float*)(ws + 12582912);      // 4*8*4096*4  = 524288
  float* attn_o = (float*)(ws + 13107200);      // 192*4096*4  = 3145728 (end 16252928)

  // OT=12: grid (16,48)=768 blocks = 3 blocks/CU (vs OT=36 @ 256 blocks = 1/CU, 10% occ)
  gemm192<12><<<dim3(16, 48), 256, 0, stream>>>(w_qkv, x, qkv);
  dwconv3<<<dim3(9216), 256, 0, stream>>>(qkv, w_dw, qkvd);
  nvpack<<<dim3(128), 256, 0, stream>>>(qkvd, (u32*)Qh, (u32*)Kh, (u32*)Vt);
  attn<<<dim3(1024), 256, 0, stream>>>(Qh, Kh, Vt, pnum, pden);
  combine<<<dim3(128), 256, 0, stream>>>(pnum, pden, attn_o);
  // OT=6: grid (16,32)=512 blocks = 2 blocks/CU
  gemm192<6><<<dim3(16, 32), 256, 0, stream>>>(w_proj, attn_o, out);
}